// Round 1
// baseline (281.911 us; speedup 1.0000x reference)
//
#include <hip/hip_runtime.h>

#define BATCH 4
#define SEQ   4096
#define DIM   128
#define BM    64      // q rows per block (4 waves x 16)
#define BN    64      // keys per tile
#define KTILES (SEQ / BN)

#define QK_STRIDE 136   // u16 stride for Qs/Ks rows (272B, 16B aligned, bank-friendly)
#define VT_STRIDE 72    // u16 stride for Vt/Ps rows (144B, 16B aligned)

typedef __attribute__((ext_vector_type(8))) __bf16 bf16x8;
typedef __attribute__((ext_vector_type(8))) unsigned short u16x8;
typedef __attribute__((ext_vector_type(4))) float f32x4;

__device__ __forceinline__ unsigned short f2bf(float f) {
    union { float f; unsigned u; } x; x.f = f;
    unsigned u = x.u;
    u += 0x7fff + ((u >> 16) & 1);   // round-to-nearest-even
    return (unsigned short)(u >> 16);
}

__device__ __forceinline__ bf16x8 lds_frag(const unsigned short* p) {
    u16x8 t = *(const u16x8*)p;
    return __builtin_bit_cast(bf16x8, t);
}

extern "C" __global__ __launch_bounds__(256, 2)
void fa_kernel(const float* __restrict__ q, const float* __restrict__ k,
               const float* __restrict__ v, float* __restrict__ out)
{
    __shared__ __align__(16) unsigned short Qs[BM * QK_STRIDE];
    __shared__ __align__(16) unsigned short Ks[BN * QK_STRIDE];
    __shared__ __align__(16) unsigned short Vt[DIM * VT_STRIDE];
    __shared__ __align__(16) unsigned short Ps[4 * 16 * VT_STRIDE];

    const int tid  = threadIdx.x;
    const int wv   = tid >> 6;
    const int lane = tid & 63;
    const int l16  = lane & 15;
    const int quad = lane >> 4;

    // XCD-aware swizzle: batch pinned to an XCD pair for K/V L2 locality
    const int bid = blockIdx.x;
    const int xcd = bid & 7;
    const int b   = xcd >> 1;
    const int qt  = ((bid >> 3) << 1) | (xcd & 1);
    const int q0  = qt * BM;

    const float scale = 0.08838834764831845f;  // 1/sqrt(128)

    const float4* q4 = (const float4*)q;
    const float4* k4 = (const float4*)k;
    const float4* v4 = (const float4*)v;

    // ---- stage Q tile once (pre-scaled), 64x128 fp32 -> bf16 ----
#pragma unroll
    for (int i = 0; i < 8; ++i) {
        int idx = tid + i * 256;
        int row = idx >> 5, c4 = idx & 31;
        float4 f = q4[(b * SEQ + q0 + row) * 32 + c4];
        ushort4 u;
        u.x = f2bf(f.x * scale); u.y = f2bf(f.y * scale);
        u.z = f2bf(f.z * scale); u.w = f2bf(f.w * scale);
        *(ushort4*)&Qs[row * QK_STRIDE + c4 * 4] = u;
    }

    float m_run[4], l_run[4];
    f32x4 accO[8];
#pragma unroll
    for (int r = 0; r < 4; ++r) { m_run[r] = -__builtin_inff(); l_run[r] = 0.f; }
#pragma unroll
    for (int ob = 0; ob < 8; ++ob) accO[ob] = (f32x4){0.f, 0.f, 0.f, 0.f};

    for (int kt = 0; kt < KTILES; ++kt) {
        __syncthreads();   // protect Ks/Vt from previous iteration's readers
        const int kbase = kt * BN;

        // ---- stage K tile row-major bf16 ----
#pragma unroll
        for (int i = 0; i < 8; ++i) {
            int idx = tid + i * 256;
            int row = idx >> 5, c4 = idx & 31;
            float4 f = k4[(b * SEQ + kbase + row) * 32 + c4];
            ushort4 u;
            u.x = f2bf(f.x); u.y = f2bf(f.y); u.z = f2bf(f.z); u.w = f2bf(f.w);
            *(ushort4*)&Ks[row * QK_STRIDE + c4 * 4] = u;
        }
        // ---- stage V tile transposed: Vt[feature][key] ----
#pragma unroll
        for (int i = 0; i < 8; ++i) {
            int idx = tid + i * 256;
            int c4 = idx >> 6, key = idx & 63;   // lanes sweep keys -> conflict-free LDS writes
            float4 f = v4[(b * SEQ + kbase + key) * 32 + c4];
            Vt[(c4 * 4 + 0) * VT_STRIDE + key] = f2bf(f.x);
            Vt[(c4 * 4 + 1) * VT_STRIDE + key] = f2bf(f.y);
            Vt[(c4 * 4 + 2) * VT_STRIDE + key] = f2bf(f.z);
            Vt[(c4 * 4 + 3) * VT_STRIDE + key] = f2bf(f.w);
        }
        __syncthreads();

        // ---- S = (Q*scale) K^T : 16x64 per wave ----
        f32x4 sfrag[4];
#pragma unroll
        for (int nb = 0; nb < 4; ++nb) sfrag[nb] = (f32x4){0.f, 0.f, 0.f, 0.f};
#pragma unroll
        for (int kc = 0; kc < 4; ++kc) {
            bf16x8 a = lds_frag(&Qs[(wv * 16 + l16) * QK_STRIDE + kc * 32 + quad * 8]);
#pragma unroll
            for (int nb = 0; nb < 4; ++nb) {
                bf16x8 bb = lds_frag(&Ks[(nb * 16 + l16) * QK_STRIDE + kc * 32 + quad * 8]);
                sfrag[nb] = __builtin_amdgcn_mfma_f32_16x16x32_bf16(a, bb, sfrag[nb], 0, 0, 0);
            }
        }

        // ---- online softmax (rows live across the 16 lanes of a quad) ----
        float alpha[4];
        float p[4][4];
#pragma unroll
        for (int r = 0; r < 4; ++r) {
            float mx = fmaxf(fmaxf(sfrag[0][r], sfrag[1][r]), fmaxf(sfrag[2][r], sfrag[3][r]));
            mx = fmaxf(mx, __shfl_xor(mx, 1));
            mx = fmaxf(mx, __shfl_xor(mx, 2));
            mx = fmaxf(mx, __shfl_xor(mx, 4));
            mx = fmaxf(mx, __shfl_xor(mx, 8));
            float mnew = fmaxf(m_run[r], mx);
            float al = __expf(m_run[r] - mnew);
            m_run[r] = mnew;
            alpha[r] = al;
            float rs = 0.f;
#pragma unroll
            for (int nb = 0; nb < 4; ++nb) {
                float pe = __expf(sfrag[nb][r] - mnew);
                p[nb][r] = pe;
                rs += pe;
            }
            rs += __shfl_xor(rs, 1);
            rs += __shfl_xor(rs, 2);
            rs += __shfl_xor(rs, 4);
            rs += __shfl_xor(rs, 8);
            l_run[r] = l_run[r] * al + rs;
        }
#pragma unroll
        for (int ob = 0; ob < 8; ++ob)
#pragma unroll
            for (int r = 0; r < 4; ++r)
                accO[ob][r] *= alpha[r];

        // ---- P: C-layout regs -> A-layout via per-wave LDS round-trip ----
        unsigned short* Pw = &Ps[wv * 16 * VT_STRIDE];
        __asm__ volatile("" ::: "memory");   // keep stores after prior-tile Ps reads
#pragma unroll
        for (int nb = 0; nb < 4; ++nb)
#pragma unroll
            for (int r = 0; r < 4; ++r)
                Pw[(quad * 4 + r) * VT_STRIDE + nb * 16 + l16] = f2bf(p[nb][r]);
        __asm__ volatile("" ::: "memory");   // keep Ps reads after stores

        // ---- O += P V ----
#pragma unroll
        for (int kk = 0; kk < 2; ++kk) {
            bf16x8 a = lds_frag(&Pw[l16 * VT_STRIDE + kk * 32 + quad * 8]);
#pragma unroll
            for (int ob = 0; ob < 8; ++ob) {
                bf16x8 bb = lds_frag(&Vt[(ob * 16 + l16) * VT_STRIDE + kk * 32 + quad * 8]);
                accO[ob] = __builtin_amdgcn_mfma_f32_16x16x32_bf16(a, bb, accO[ob], 0, 0, 0);
            }
        }
    }

    // ---- epilogue: divide by l, store fp32 ----
    float* outp = out + (b * SEQ + q0 + wv * 16) * DIM;
#pragma unroll
    for (int r = 0; r < 4; ++r) {
        float inv = 1.f / l_run[r];
        int row = quad * 4 + r;
#pragma unroll
        for (int ob = 0; ob < 8; ++ob)
            outp[row * DIM + ob * 16 + l16] = accO[ob][r] * inv;
    }
}

extern "C" void kernel_launch(void* const* d_in, const int* in_sizes, int n_in,
                              void* d_out, int out_size, void* d_ws, size_t ws_size,
                              hipStream_t stream) {
    const float* q = (const float*)d_in[0];
    const float* k = (const float*)d_in[1];
    const float* v = (const float*)d_in[2];
    float* out = (float*)d_out;
    dim3 grid(BATCH * (SEQ / BM));   // 256 blocks
    dim3 block(256);
    hipLaunchKernelGGL(fa_kernel, grid, block, 0, stream, q, k, v, out);
}

// Round 2
// 198.854 us; speedup vs baseline: 1.4177x; 1.4177x over previous
//
#include <hip/hip_runtime.h>

#define BATCH 4
#define SEQ   4096
#define DIM   128
#define BM    64      // q rows per block (4 q-subtiles x 16)
#define BN    64      // keys per tile
#define KTILES (SEQ / BN)   // 64
#define NGROUP 2            // in-block KV split factor
#define TPG (KTILES / NGROUP)  // 32 tiles per group

#define QK_STRIDE 136   // u16 stride for Qs/Ks rows (272B, 16B aligned)
#define VT_STRIDE 72    // u16 stride for Vt/Ps rows (144B, 16B aligned)

typedef __attribute__((ext_vector_type(8))) __bf16 bf16x8;
typedef __attribute__((ext_vector_type(8))) unsigned short u16x8;
typedef __attribute__((ext_vector_type(4))) float f32x4;

__device__ __forceinline__ unsigned short f2bf(float f) {
    __bf16 h = (__bf16)f;   // RNE; lets compiler pick v_cvt_pk_bf16_f32
    return __builtin_bit_cast(unsigned short, h);
}

__device__ __forceinline__ bf16x8 lds_frag(const unsigned short* p) {
    u16x8 t = *(const u16x8*)p;
    return __builtin_bit_cast(bf16x8, t);
}

// LDS plan (u16 units):
//   Qs : 64*136            =  8704
//   Ks : 2 groups * 64*136 = 17408
//   Vt : 2 groups * 128*72 = 18432
//   Ps : 8 waves * 16*72   =  9216
//   total 53760 u16 = 107520 B  (1 block/CU, 8 waves)
#define LDS_U16 53760

extern "C" __global__ __launch_bounds__(512, 2)
void fa_kernel(const float* __restrict__ q, const float* __restrict__ k,
               const float* __restrict__ v, float* __restrict__ out)
{
    __shared__ __align__(16) unsigned short lds[LDS_U16];
    unsigned short* Qs     = lds;
    unsigned short* KsBase = lds + 64 * QK_STRIDE;
    unsigned short* VtBase = KsBase + 2 * 64 * QK_STRIDE;
    unsigned short* PsBase = VtBase + 2 * 128 * VT_STRIDE;

    const int tid  = threadIdx.x;
    const int wv   = tid >> 6;        // 0..7
    const int lane = tid & 63;
    const int l16  = lane & 15;
    const int quad = lane >> 4;
    const int g    = wv >> 2;         // KV group (0/1)
    const int wq   = wv & 3;          // q sub-tile within block
    const int gt   = tid & 255;       // thread id within group

    unsigned short* Ks = KsBase + g * 64 * QK_STRIDE;
    unsigned short* Vt = VtBase + g * 128 * VT_STRIDE;
    unsigned short* Pw = PsBase + wv * 16 * VT_STRIDE;

    // XCD-aware swizzle: batch pinned to an XCD pair for K/V L2 locality
    const int bid = blockIdx.x;
    const int xcd = bid & 7;
    const int b   = xcd >> 1;
    const int qt  = ((bid >> 3) << 1) | (xcd & 1);
    const int q0  = qt * BM;

    const float scale = 0.08838834764831845f;  // 1/sqrt(128)

    const float4* q4 = (const float4*)q;
    const float4* k4 = (const float4*)k;
    const float4* v4 = (const float4*)v;

    // ---- stage Q tile once (pre-scaled), 64x128 fp32 -> bf16 ----
#pragma unroll
    for (int i = 0; i < 4; ++i) {
        int idx = tid + i * 512;
        int row = idx >> 5, c4 = idx & 31;
        float4 f = q4[(b * SEQ + q0 + row) * 32 + c4];
        ushort4 u;
        u.x = f2bf(f.x * scale); u.y = f2bf(f.y * scale);
        u.z = f2bf(f.z * scale); u.w = f2bf(f.w * scale);
        *(ushort4*)&Qs[row * QK_STRIDE + c4 * 4] = u;
    }

    // ---- prefetch this group's first KV tile into registers ----
    float4 ldK[8], ldV[8];
    {
        const int kbase = g * BN;
#pragma unroll
        for (int i = 0; i < 8; ++i) {
            int idx = gt + i * 256;
            ldK[i] = k4[(b * SEQ + kbase + (idx >> 5)) * 32 + (idx & 31)];
        }
#pragma unroll
        for (int i = 0; i < 8; ++i) {
            int idx = gt + i * 256;
            ldV[i] = v4[(b * SEQ + kbase + (idx & 63)) * 32 + (idx >> 6)];
        }
    }

    float m_run[4], l_run[4];
    f32x4 accO[8];
#pragma unroll
    for (int r = 0; r < 4; ++r) { m_run[r] = -__builtin_inff(); l_run[r] = 0.f; }
#pragma unroll
    for (int ob = 0; ob < 8; ++ob) accO[ob] = (f32x4){0.f, 0.f, 0.f, 0.f};

    for (int t = 0; t < TPG; ++t) {
        __syncthreads();   // previous tile's Ks/Vt consumers done (t=0: Qs visible)

        // ---- commit prefetched K tile (row-major bf16) ----
#pragma unroll
        for (int i = 0; i < 8; ++i) {
            int idx = gt + i * 256;
            int row = idx >> 5, c4 = idx & 31;
            float4 f = ldK[i];
            ushort4 u;
            u.x = f2bf(f.x); u.y = f2bf(f.y); u.z = f2bf(f.z); u.w = f2bf(f.w);
            *(ushort4*)&Ks[row * QK_STRIDE + c4 * 4] = u;
        }
        // ---- commit prefetched V tile transposed: Vt[feature][key] ----
#pragma unroll
        for (int i = 0; i < 8; ++i) {
            int idx = gt + i * 256;
            int c4 = idx >> 6, key = idx & 63;   // lanes sweep keys -> conflict-free writes
            float4 f = ldV[i];
            Vt[(c4 * 4 + 0) * VT_STRIDE + key] = f2bf(f.x);
            Vt[(c4 * 4 + 1) * VT_STRIDE + key] = f2bf(f.y);
            Vt[(c4 * 4 + 2) * VT_STRIDE + key] = f2bf(f.z);
            Vt[(c4 * 4 + 3) * VT_STRIDE + key] = f2bf(f.w);
        }
        __syncthreads();

        // ---- issue next tile's global loads; they land during compute ----
        if (t + 1 < TPG) {
            const int kbase = ((t + 1) * NGROUP + g) * BN;
#pragma unroll
            for (int i = 0; i < 8; ++i) {
                int idx = gt + i * 256;
                ldK[i] = k4[(b * SEQ + kbase + (idx >> 5)) * 32 + (idx & 31)];
            }
#pragma unroll
            for (int i = 0; i < 8; ++i) {
                int idx = gt + i * 256;
                ldV[i] = v4[(b * SEQ + kbase + (idx & 63)) * 32 + (idx >> 6)];
            }
        }

        // ---- S = (Q*scale) K^T : 16x64 per wave ----
        f32x4 sfrag[4];
#pragma unroll
        for (int nb = 0; nb < 4; ++nb) sfrag[nb] = (f32x4){0.f, 0.f, 0.f, 0.f};
#pragma unroll
        for (int kc = 0; kc < 4; ++kc) {
            bf16x8 a = lds_frag(&Qs[(wq * 16 + l16) * QK_STRIDE + kc * 32 + quad * 8]);
#pragma unroll
            for (int nb = 0; nb < 4; ++nb) {
                bf16x8 bb = lds_frag(&Ks[(nb * 16 + l16) * QK_STRIDE + kc * 32 + quad * 8]);
                sfrag[nb] = __builtin_amdgcn_mfma_f32_16x16x32_bf16(a, bb, sfrag[nb], 0, 0, 0);
            }
        }

        // ---- online softmax (rows live across the 16 lanes of a quad) ----
        float alpha[4];
        float p[4][4];
#pragma unroll
        for (int r = 0; r < 4; ++r) {
            float mx = fmaxf(fmaxf(sfrag[0][r], sfrag[1][r]), fmaxf(sfrag[2][r], sfrag[3][r]));
            mx = fmaxf(mx, __shfl_xor(mx, 1));
            mx = fmaxf(mx, __shfl_xor(mx, 2));
            mx = fmaxf(mx, __shfl_xor(mx, 4));
            mx = fmaxf(mx, __shfl_xor(mx, 8));
            float mnew = fmaxf(m_run[r], mx);
            float al = __expf(m_run[r] - mnew);
            m_run[r] = mnew;
            alpha[r] = al;
            float rs = 0.f;
#pragma unroll
            for (int nb = 0; nb < 4; ++nb) {
                float pe = __expf(sfrag[nb][r] - mnew);
                p[nb][r] = pe;
                rs += pe;
            }
            rs += __shfl_xor(rs, 1);
            rs += __shfl_xor(rs, 2);
            rs += __shfl_xor(rs, 4);
            rs += __shfl_xor(rs, 8);
            l_run[r] = l_run[r] * al + rs;
        }
#pragma unroll
        for (int ob = 0; ob < 8; ++ob)
#pragma unroll
            for (int r = 0; r < 4; ++r)
                accO[ob][r] *= alpha[r];

        // ---- P: C-layout regs -> A-layout via per-wave LDS round-trip ----
        __asm__ volatile("" ::: "memory");
#pragma unroll
        for (int nb = 0; nb < 4; ++nb)
#pragma unroll
            for (int r = 0; r < 4; ++r)
                Pw[(quad * 4 + r) * VT_STRIDE + nb * 16 + l16] = f2bf(p[nb][r]);
        __asm__ volatile("" ::: "memory");

        // ---- O += P V ----
#pragma unroll
        for (int kk = 0; kk < 2; ++kk) {
            bf16x8 a = lds_frag(&Pw[l16 * VT_STRIDE + kk * 32 + quad * 8]);
#pragma unroll
            for (int ob = 0; ob < 8; ++ob) {
                bf16x8 bb = lds_frag(&Vt[(ob * 16 + l16) * VT_STRIDE + kk * 32 + quad * 8]);
                accO[ob] = __builtin_amdgcn_mfma_f32_16x16x32_bf16(a, bb, accO[ob], 0, 0, 0);
            }
        }
    }

    // ---- merge the two KV groups (reuse Qs/Ks LDS region), then store ----
    __syncthreads();   // all consumers of Ks/Vt/Ps done
    float* mlbuf = (float*)lds;            // 4 slots * 64 lanes * 8 floats = 8 KB
    float* obuf  = ((float*)lds) + 2048;   // 4 slots * 64 lanes * 32 floats = 32 KB
    if (g == 1) {
#pragma unroll
        for (int r = 0; r < 4; ++r) {
            mlbuf[(wq * 64 + lane) * 8 + r * 2 + 0] = m_run[r];
            mlbuf[(wq * 64 + lane) * 8 + r * 2 + 1] = l_run[r];
        }
#pragma unroll
        for (int ob = 0; ob < 8; ++ob)
#pragma unroll
            for (int r = 0; r < 4; ++r)
                obuf[(wq * 64 + lane) * 32 + ob * 4 + r] = accO[ob][r];
    }
    __syncthreads();
    if (g == 0) {
#pragma unroll
        for (int r = 0; r < 4; ++r) {
            float m1 = mlbuf[(wq * 64 + lane) * 8 + r * 2 + 0];
            float l1 = mlbuf[(wq * 64 + lane) * 8 + r * 2 + 1];
            float mx = fmaxf(m_run[r], m1);
            float a0 = __expf(m_run[r] - mx);
            float a1 = __expf(m1 - mx);
            float inv = 1.f / (a0 * l_run[r] + a1 * l1);
            int row = quad * 4 + r;
            float* outp = out + (b * SEQ + q0 + wq * 16 + row) * DIM;
#pragma unroll
            for (int ob = 0; ob < 8; ++ob) {
                float o1 = obuf[(wq * 64 + lane) * 32 + ob * 4 + r];
                outp[ob * 16 + l16] = (a0 * accO[ob][r] + a1 * o1) * inv;
            }
        }
    }
}

extern "C" void kernel_launch(void* const* d_in, const int* in_sizes, int n_in,
                              void* d_out, int out_size, void* d_ws, size_t ws_size,
                              hipStream_t stream) {
    const float* q = (const float*)d_in[0];
    const float* k = (const float*)d_in[1];
    const float* v = (const float*)d_in[2];
    float* out = (float*)d_out;
    dim3 grid(BATCH * (SEQ / BM));   // 256 blocks, 1 per CU
    dim3 block(512);                 // 8 waves: 4 q-subtiles x 2 KV groups
    hipLaunchKernelGGL(fa_kernel, grid, block, 0, stream, q, k, v, out);
}